// Round 1
// baseline (18576.262 us; speedup 1.0000x reference)
//
#include <hip/hip_runtime.h>
#include <hip/hip_bf16.h>
#include <math.h>

// Problem constants
#define BB 2
#define NN 1024
#define HID 2048
#define NH 16
#define KVH 4
#define DD 128
#define L_TOTAL 32768   // B*H*N flattened scan length
#define TOK 2048        // B*N tokens

typedef __bf16 bf16;
typedef __bf16 bf16x8 __attribute__((ext_vector_type(8)));
typedef float f32x4 __attribute__((ext_vector_type(4)));

// ---------------------------------------------------------------------------
// Generic MFMA GEMM:  C[m,n] = sum_k A[m,k] * BT[n,k]
// A, BT bf16 (optionally split hi/lo for ~fp32 accuracy), C fp32 or bf16.
// Each wave computes one 16x16 tile (m90-style; optimize later).
// Batch addressing: z = blockIdx.z + z0; b = z/zH; h = z%zH;
//   Aoff = b*aSb + h*aSh + blockIdx.z*aSz
//   Boff = b*bSb + (h>>gShift)*bSh
//   Coff = blockIdx.z*cSz
// ---------------------------------------------------------------------------
template<bool SPLIT, bool OUTBF>
__global__ __launch_bounds__(256)
void gemm_bt(const bf16* __restrict__ A, const bf16* __restrict__ Alo,
             const bf16* __restrict__ B, const bf16* __restrict__ Blo,
             float* __restrict__ Cf, bf16* __restrict__ Cb,
             int M, int N, int K, int lda, int ldb, int ldc,
             long aSb, long aSh, long aSz, long bSb, long bSh, long cSz,
             int zH, int gShift, int z0)
{
    const int zc   = blockIdx.z;
    const int z    = zc + z0;
    const int b    = z / zH;
    const int h    = z % zH;
    const int lane = threadIdx.x & 63;
    const int wave = threadIdx.x >> 6;
    const int tiles_n = N >> 4;
    const int tile = blockIdx.x * 4 + wave;
    const int mt   = tile / tiles_n;
    const int nt   = tile % tiles_n;

    const long aoff = (long)b * aSb + (long)h * aSh + (long)zc * aSz;
    const long boff = (long)b * bSb + (long)(h >> gShift) * bSh;

    const bf16* ap = A + aoff + (long)(mt * 16 + (lane & 15)) * lda + ((lane >> 4) << 3);
    const bf16* bp = B + boff + (long)(nt * 16 + (lane & 15)) * ldb + ((lane >> 4) << 3);

    f32x4 acc = {0.f, 0.f, 0.f, 0.f};
    if (!SPLIT) {
        for (int k0 = 0; k0 < K; k0 += 32) {
            bf16x8 av = *(const bf16x8*)ap;
            bf16x8 bv = *(const bf16x8*)bp;
            acc = __builtin_amdgcn_mfma_f32_16x16x32_bf16(av, bv, acc, 0, 0, 0);
            ap += 32; bp += 32;
        }
    } else {
        const bf16* apl = Alo + (ap - A);
        const bf16* bpl = Blo + (bp - B);
        for (int k0 = 0; k0 < K; k0 += 32) {
            bf16x8 av = *(const bf16x8*)ap;
            bf16x8 bv = *(const bf16x8*)bp;
            bf16x8 al = *(const bf16x8*)apl;
            bf16x8 bl = *(const bf16x8*)bpl;
            acc = __builtin_amdgcn_mfma_f32_16x16x32_bf16(av, bv, acc, 0, 0, 0);
            acc = __builtin_amdgcn_mfma_f32_16x16x32_bf16(al, bv, acc, 0, 0, 0);
            acc = __builtin_amdgcn_mfma_f32_16x16x32_bf16(av, bl, acc, 0, 0, 0);
            ap += 32; bp += 32; apl += 32; bpl += 32;
        }
    }

    // C/D layout (m89/m91-verified): col = lane&15, row = (lane>>4)*4 + r
    const long cbase = (long)zc * cSz + (long)(nt * 16 + (lane & 15));
    const int  r0    = mt * 16 + ((lane >> 4) << 2);
    #pragma unroll
    for (int r = 0; r < 4; ++r) {
        long idx = cbase + (long)(r0 + r) * ldc;
        if (OUTBF) Cb[idx] = (bf16)acc[r];
        else       Cf[idx] = acc[r];
    }
}

// ---------------------------------------------------------------------------
// Elementwise helpers
// ---------------------------------------------------------------------------
__global__ void cast_split_k(const float* __restrict__ in, bf16* __restrict__ hi,
                             bf16* __restrict__ lo, long n)
{
    long i = (long)blockIdx.x * blockDim.x + threadIdx.x;
    if (i < n) {
        float x = in[i];
        bf16 h = (bf16)x;
        hi[i] = h;
        lo[i] = (bf16)(x - (float)h);
    }
}

__global__ void cast_k(const float* __restrict__ in, bf16* __restrict__ out, long n)
{
    long i = (long)blockIdx.x * blockDim.x + threadIdx.x;
    if (i < n) out[i] = (bf16)in[i];
}

// out[n*K + k] = in[k*N + n]  (transpose + split-cast), in is K x N row-major
__global__ void transpose_split_k(const float* __restrict__ in, bf16* __restrict__ hi,
                                  bf16* __restrict__ lo, int K, int N)
{
    long i = (long)blockIdx.x * blockDim.x + threadIdx.x;
    if (i < (long)K * N) {
        int n = (int)(i / K);
        int k = (int)(i % K);
        float x = in[(long)k * N + n];
        bf16 h = (bf16)x;
        hi[i] = h;
        lo[i] = (bf16)(x - (float)h);
    }
}

// v (tok, kvh*128+d) -> vT ((b,kvh,d), m) bf16
__global__ void vtrans_k(const float* __restrict__ v, bf16* __restrict__ vT)
{
    long i = (long)blockIdx.x * blockDim.x + threadIdx.x;
    if (i < 1048576) {
        int m   = (int)(i & 1023);
        int d   = (int)((i >> 10) & 127);
        int kvh = (int)((i >> 17) & 3);
        int b   = (int)(i >> 19);
        vT[i] = (bf16)v[((long)(b * 1024 + m)) * 512 + kvh * 128 + d];
    }
}

// Row softmax over contiguous 128 floats, one wave per row
__global__ void softmax128_k(const float* __restrict__ in, float* __restrict__ out)
{
    const int row  = blockIdx.x;
    const int lane = threadIdx.x;
    float2 v = ((const float2*)(in + (long)row * 128))[lane];
    float m = fmaxf(v.x, v.y);
    #pragma unroll
    for (int s = 1; s < 64; s <<= 1) m = fmaxf(m, __shfl_xor(m, s, 64));
    float ex = expf(v.x - m), ey = expf(v.y - m);
    float sum = ex + ey;
    #pragma unroll
    for (int s = 1; s < 64; s <<= 1) sum += __shfl_xor(sum, s, 64);
    float inv = 1.0f / sum;
    ((float2*)(out + (long)row * 128))[lane] = make_float2(ex * inv, ey * inv);
}

// gl = log_sigmoid(x)/16, numerically stable
__global__ void logsig_k(const float* __restrict__ in, float* __restrict__ out, long n)
{
    long i = (long)blockIdx.x * blockDim.x + threadIdx.x;
    if (i < n) {
        float x = in[i];
        float l = log1pf(expf(-fabsf(x)));
        out[i] = (fminf(x, 0.f) - l) * 0.0625f;
    }
}

// Causal softmax over 1024-wide bf16 score rows (in place), one wave per row
__global__ void softmax_causal_k(bf16* __restrict__ P)
{
    const int row  = blockIdx.x;
    const int qi   = row & 1023;
    const int lane = threadIdx.x;
    bf16* p = P + (long)row * 1024;
    const float scale = 0.08838834764831845f;  // 1/sqrt(128)
    float vals[16];
    float m = -3.0e38f;
    #pragma unroll
    for (int t = 0; t < 16; ++t) {
        int j = lane + t * 64;
        float x = (j <= qi) ? (float)p[j] * scale : -3.0e38f;
        vals[t] = x;
        m = fmaxf(m, x);
    }
    #pragma unroll
    for (int s = 1; s < 64; s <<= 1) m = fmaxf(m, __shfl_xor(m, s, 64));
    float sum = 0.f;
    #pragma unroll
    for (int t = 0; t < 16; ++t) {
        float e = (vals[t] > -1.0e38f) ? expf(vals[t] - m) : 0.f;
        vals[t] = e;
        sum += e;
    }
    #pragma unroll
    for (int s = 1; s < 64; s <<= 1) sum += __shfl_xor(sum, s, 64);
    float inv = 1.f / sum;
    #pragma unroll
    for (int t = 0; t < 16; ++t) {
        int j = lane + t * 64;
        p[j] = (bf16)(vals[t] * inv);
    }
}

// ---------------------------------------------------------------------------
// Delta-rule scan over the flattened (B*H*N)=32768 sequence.
// Per-column independence: block bi handles columns j0=2*bi, j0+1.
// One wave; lane holds state rows (2*lane, 2*lane+1) for both columns.
// Token ell: b=ell>>14, h=(ell>>10)&15, n=ell&1023.
//   u_j = g_j*(v_j - k.s_j);  s_j += u_j*k;  o_j = q.s_j(prev) + (q.k)*u_j
// ---------------------------------------------------------------------------
__global__ void delta_scan_k(const float* __restrict__ QL, const float* __restrict__ KL,
                             const float* __restrict__ GL, const float* __restrict__ V,
                             float* __restrict__ O)
{
    const int lane = threadIdx.x;
    const int j0   = blockIdx.x << 1;
    float sA0 = 0.f, sB0 = 0.f, sA1 = 0.f, sB1 = 0.f;

    long rq, rk;
    {
        int b = 0, h = 0, n = 0;
        (void)b; (void)h; (void)n;
        rq = 0; rk = 0;
    }
    float2 kv = ((const float2*)(KL + rk))[lane];
    float2 qv = ((const float2*)(QL + rq))[lane];
    float2 vv = *(const float2*)(V + rk + j0);
    float2 gv = *(const float2*)(GL + rk + j0);

    for (int l = 0; l < L_TOTAL; ++l) {
        // prefetch next token (independent of state -> overlaps reduce chain)
        float2 kvn, qvn, vvn, gvn;
        {
            int ln = (l + 1 < L_TOTAL) ? l + 1 : l;
            int b = ln >> 14, h = (ln >> 10) & 15, n = ln & 1023;
            long rowbase = (long)((b << 10) | n);
            long rqn = rowbase * 2048 + h * 128;
            long rkn = rowbase * 512 + ((h >> 2) << 7);
            kvn = ((const float2*)(KL + rkn))[lane];
            qvn = ((const float2*)(QL + rqn))[lane];
            vvn = *(const float2*)(V + rkn + j0);
            gvn = *(const float2*)(GL + rkn + j0);
        }

        float pks0 = kv.x * sA0 + kv.y * sB0;
        float pks1 = kv.x * sA1 + kv.y * sB1;
        float pqs0 = qv.x * sA0 + qv.y * sB0;
        float pqs1 = qv.x * sA1 + qv.y * sB1;
        float pqk  = qv.x * kv.x + qv.y * kv.y;
        #pragma unroll
        for (int s = 1; s < 64; s <<= 1) {
            pks0 += __shfl_xor(pks0, s, 64);
            pks1 += __shfl_xor(pks1, s, 64);
            pqs0 += __shfl_xor(pqs0, s, 64);
            pqs1 += __shfl_xor(pqs1, s, 64);
            pqk  += __shfl_xor(pqk,  s, 64);
        }
        float u0 = gv.x * (vv.x - pks0);
        float u1 = gv.y * (vv.y - pks1);
        if (lane == 0) {
            float o0 = pqs0 + pqk * u0;
            float o1 = pqs1 + pqk * u1;
            *(float2*)(O + (long)l * 128 + j0) = make_float2(o0, o1);
        }
        sA0 += u0 * kv.x; sB0 += u0 * kv.y;
        sA1 += u1 * kv.x; sB1 += u1 * kv.y;
        kv = kvn; qv = qvn; vv = vvn; gv = gvn;
    }
}

// oComb[(b,n),(h,d)] = 0.5*(oLin[(b,h,n),d] + oBase[(b,h,n),d])  -> bf16
__global__ void combine_k(const float* __restrict__ oLin, const bf16* __restrict__ oBase,
                          bf16* __restrict__ oComb, long n)
{
    long i = (long)blockIdx.x * blockDim.x + threadIdx.x;
    if (i < n) {
        int d  = (int)(i & 127);
        int hh = (int)((i >> 7) & 15);
        int nn = (int)((i >> 11) & 1023);
        int b  = (int)(i >> 21);
        long src = ((long)((b * 16 + hh) * 1024 + nn)) * 128 + d;
        oComb[i] = (bf16)(0.5f * (oLin[src] + (float)oBase[src]));
    }
}

// ---------------------------------------------------------------------------
extern "C" void kernel_launch(void* const* d_in, const int* in_sizes, int n_in,
                              void* d_out, int out_size, void* d_ws, size_t ws_size,
                              hipStream_t stream)
{
    const float* hs = (const float*)d_in[0];
    const float* Wq = (const float*)d_in[1];
    const float* Wk = (const float*)d_in[2];
    const float* Wv = (const float*)d_in[3];
    const float* Wo = (const float*)d_in[4];

    char* base = (char*)d_ws;
    size_t off = 0;
    auto alloc = [&](size_t bytes) -> char* {
        char* r = base + off;
        off += (bytes + 255) & ~(size_t)255;
        return r;
    };

    bf16* hsHi  = (bf16*)alloc((long)TOK * 2048 * 2);
    bf16* hsLo  = (bf16*)alloc((long)TOK * 2048 * 2);
    bf16* WqTHi = (bf16*)alloc(2048L * 2048 * 2);
    bf16* WqTLo = (bf16*)alloc(2048L * 2048 * 2);
    bf16* WkTHi = (bf16*)alloc(512L * 2048 * 2);
    bf16* WkTLo = (bf16*)alloc(512L * 2048 * 2);
    bf16* WvTHi = (bf16*)alloc(512L * 2048 * 2);
    bf16* WvTLo = (bf16*)alloc(512L * 2048 * 2);
    bf16* WoTHi = (bf16*)alloc(2048L * 2048 * 2);
    bf16* WoTLo = (bf16*)alloc(2048L * 2048 * 2);
    float* qf   = (float*)alloc((long)TOK * 2048 * 4);
    float* kf   = (float*)alloc((long)TOK * 512 * 4);
    float* vf   = (float*)alloc((long)TOK * 512 * 4);
    float* QLb  = (float*)alloc((long)TOK * 2048 * 4);
    float* KLb  = (float*)alloc((long)TOK * 512 * 4);
    float* GLb  = (float*)alloc((long)TOK * 512 * 4);
    bf16* qhB   = (bf16*)alloc((long)TOK * 2048 * 2);
    bf16* khB   = (bf16*)alloc((long)TOK * 512 * 2);
    bf16* vT    = (bf16*)alloc(1048576L * 2);
    bf16* P     = (bf16*)alloc(8L * 1024 * 1024 * 2);
    float* oLin = (float*)alloc(32768L * 128 * 4);
    bf16* oBase = (bf16*)alloc(32768L * 128 * 2);
    bf16* oComb = (bf16*)alloc((long)TOK * 2048 * 2);

    const int T256 = 256;
    // casts / transposes
    cast_split_k<<<(TOK * 2048 + 255) / 256, T256, 0, stream>>>(hs, hsHi, hsLo, (long)TOK * 2048);
    transpose_split_k<<<(2048L * 2048 + 255) / 256, T256, 0, stream>>>(Wq, WqTHi, WqTLo, 2048, 2048);
    transpose_split_k<<<(2048L * 512 + 255) / 256, T256, 0, stream>>>(Wk, WkTHi, WkTLo, 2048, 512);
    transpose_split_k<<<(2048L * 512 + 255) / 256, T256, 0, stream>>>(Wv, WvTHi, WvTLo, 2048, 512);
    transpose_split_k<<<(2048L * 2048 + 255) / 256, T256, 0, stream>>>(Wo, WoTHi, WoTLo, 2048, 2048);

    // projections (split-bf16 ~ fp32 accuracy; outputs feed the unstable scan)
    gemm_bt<true, false><<<dim3(4096, 1, 1), T256, 0, stream>>>(
        hsHi, hsLo, WqTHi, WqTLo, qf, nullptr,
        2048, 2048, 2048, 2048, 2048, 2048, 0, 0, 0, 0, 0, 0, 1, 0, 0);
    gemm_bt<true, false><<<dim3(1024, 1, 1), T256, 0, stream>>>(
        hsHi, hsLo, WkTHi, WkTLo, kf, nullptr,
        2048, 512, 2048, 2048, 2048, 512, 0, 0, 0, 0, 0, 0, 1, 0, 0);
    gemm_bt<true, false><<<dim3(1024, 1, 1), T256, 0, stream>>>(
        hsHi, hsLo, WvTHi, WvTLo, vf, nullptr,
        2048, 512, 2048, 2048, 2048, 512, 0, 0, 0, 0, 0, 0, 1, 0, 0);

    // scan-input prep
    softmax128_k<<<32768, 64, 0, stream>>>(qf, QLb);
    softmax128_k<<<8192, 64, 0, stream>>>(kf, KLb);
    logsig_k<<<(1048576 + 255) / 256, T256, 0, stream>>>(kf, GLb, 1048576);

    // attention-branch inputs
    cast_k<<<(TOK * 2048 + 255) / 256, T256, 0, stream>>>(qf, qhB, (long)TOK * 2048);
    cast_k<<<(TOK * 512 + 255) / 256, T256, 0, stream>>>(kf, khB, (long)TOK * 512);
    vtrans_k<<<(1048576 + 255) / 256, T256, 0, stream>>>(vf, vT);

    // attention branch, chunked over 8 (b,h) pairs to bound the P buffer
    for (int z0 = 0; z0 < 32; z0 += 8) {
        gemm_bt<false, true><<<dim3(1024, 1, 8), T256, 0, stream>>>(
            qhB, nullptr, khB, nullptr, nullptr, P,
            1024, 1024, 128, 2048, 512, 1024,
            2097152L, 128L, 0L, 524288L, 128L, 1048576L, 16, 2, z0);
        softmax_causal_k<<<8192, 64, 0, stream>>>(P);
        gemm_bt<false, true><<<dim3(128, 1, 8), T256, 0, stream>>>(
            P, nullptr, vT, nullptr, nullptr, oBase + (long)z0 * 131072,
            1024, 128, 1024, 1024, 1024, 128,
            0L, 0L, 1048576L, 524288L, 131072L, 131072L, 16, 2, z0);
    }

    // delta-rule scan (the long pole this round)
    delta_scan_k<<<64, 64, 0, stream>>>(QLb, KLb, GLb, vf, oLin);

    // combine branches and output projection
    combine_k<<<(TOK * 2048 + 255) / 256, T256, 0, stream>>>(oLin, oBase, oComb, (long)TOK * 2048);
    gemm_bt<false, false><<<dim3(4096, 1, 1), T256, 0, stream>>>(
        oComb, nullptr, WoTHi, nullptr, (float*)d_out, nullptr,
        2048, 2048, 2048, 2048, 2048, 2048, 0, 0, 0, 0, 0, 0, 1, 0, 0);
}

// Round 3
// 8417.574 us; speedup vs baseline: 2.2068x; 2.2068x over previous
//
#include <hip/hip_runtime.h>
#include <hip/hip_bf16.h>
#include <hip/hip_fp16.h>
#include <math.h>

// Problem constants
#define BB 2
#define NN 1024
#define HID 2048
#define NH 16
#define KVH 4
#define DD 128
#define L_TOTAL 32768   // B*H*N flattened scan length
#define TOK 2048        // B*N tokens
#define NCHUNK 512      // 64-token chunks over the flattened sequence

typedef __bf16 bf16;
typedef __bf16 bf16x8 __attribute__((ext_vector_type(8)));
typedef __bf16 bf16x4 __attribute__((ext_vector_type(4)));
typedef float f32x4 __attribute__((ext_vector_type(4)));

// ---------------------------------------------------------------------------
// Generic MFMA GEMM:  C[m,n] = sum_k A[m,k] * BT[n,k]   (R1-verified)
// ---------------------------------------------------------------------------
template<bool SPLIT, bool OUTBF>
__global__ __launch_bounds__(256)
void gemm_bt(const bf16* __restrict__ A, const bf16* __restrict__ Alo,
             const bf16* __restrict__ B, const bf16* __restrict__ Blo,
             float* __restrict__ Cf, bf16* __restrict__ Cb,
             int M, int N, int K, int lda, int ldb, int ldc,
             long aSb, long aSh, long aSz, long bSb, long bSh, long cSz,
             int zH, int gShift, int z0)
{
    const int zc   = blockIdx.z;
    const int z    = zc + z0;
    const int b    = z / zH;
    const int h    = z % zH;
    const int lane = threadIdx.x & 63;
    const int wave = threadIdx.x >> 6;
    const int tiles_n = N >> 4;
    const int tile = blockIdx.x * 4 + wave;
    const int mt   = tile / tiles_n;
    const int nt   = tile % tiles_n;

    const long aoff = (long)b * aSb + (long)h * aSh + (long)zc * aSz;
    const long boff = (long)b * bSb + (long)(h >> gShift) * bSh;

    const bf16* ap = A + aoff + (long)(mt * 16 + (lane & 15)) * lda + ((lane >> 4) << 3);
    const bf16* bp = B + boff + (long)(nt * 16 + (lane & 15)) * ldb + ((lane >> 4) << 3);

    f32x4 acc = {0.f, 0.f, 0.f, 0.f};
    if (!SPLIT) {
        for (int k0 = 0; k0 < K; k0 += 32) {
            bf16x8 av = *(const bf16x8*)ap;
            bf16x8 bv = *(const bf16x8*)bp;
            acc = __builtin_amdgcn_mfma_f32_16x16x32_bf16(av, bv, acc, 0, 0, 0);
            ap += 32; bp += 32;
        }
    } else {
        const bf16* apl = Alo + (ap - A);
        const bf16* bpl = Blo + (bp - B);
        for (int k0 = 0; k0 < K; k0 += 32) {
            bf16x8 av = *(const bf16x8*)ap;
            bf16x8 bv = *(const bf16x8*)bp;
            bf16x8 al = *(const bf16x8*)apl;
            bf16x8 bl = *(const bf16x8*)bpl;
            acc = __builtin_amdgcn_mfma_f32_16x16x32_bf16(av, bv, acc, 0, 0, 0);
            acc = __builtin_amdgcn_mfma_f32_16x16x32_bf16(al, bv, acc, 0, 0, 0);
            acc = __builtin_amdgcn_mfma_f32_16x16x32_bf16(av, bl, acc, 0, 0, 0);
            ap += 32; bp += 32; apl += 32; bpl += 32;
        }
    }

    const long cbase = (long)zc * cSz + (long)(nt * 16 + (lane & 15));
    const int  r0    = mt * 16 + ((lane >> 4) << 2);
    #pragma unroll
    for (int r = 0; r < 4; ++r) {
        long idx = cbase + (long)(r0 + r) * ldc;
        if (OUTBF) Cb[idx] = (bf16)acc[r];
        else       Cf[idx] = acc[r];
    }
}

// ---------------------------------------------------------------------------
// Elementwise helpers
// ---------------------------------------------------------------------------
__global__ void cast_split_k(const float* __restrict__ in, bf16* __restrict__ hi,
                             bf16* __restrict__ lo, long n)
{
    long i = (long)blockIdx.x * blockDim.x + threadIdx.x;
    if (i < n) {
        float x = in[i];
        bf16 h = (bf16)x;
        hi[i] = h;
        lo[i] = (bf16)(x - (float)h);
    }
}

__global__ void cast_k(const float* __restrict__ in, bf16* __restrict__ out, long n)
{
    long i = (long)blockIdx.x * blockDim.x + threadIdx.x;
    if (i < n) out[i] = (bf16)in[i];
}

__global__ void transpose_split_k(const float* __restrict__ in, bf16* __restrict__ hi,
                                  bf16* __restrict__ lo, int K, int N)
{
    long i = (long)blockIdx.x * blockDim.x + threadIdx.x;
    if (i < (long)K * N) {
        int n = (int)(i / K);
        int k = (int)(i % K);
        float x = in[(long)k * N + n];
        bf16 h = (bf16)x;
        hi[i] = h;
        lo[i] = (bf16)(x - (float)h);
    }
}

__global__ void vtrans_k(const float* __restrict__ v, bf16* __restrict__ vT)
{
    long i = (long)blockIdx.x * blockDim.x + threadIdx.x;
    if (i < 1048576) {
        int m   = (int)(i & 1023);
        int d   = (int)((i >> 10) & 127);
        int kvh = (int)((i >> 17) & 3);
        int b   = (int)(i >> 19);
        vT[i] = (bf16)v[((long)(b * 1024 + m)) * 512 + kvh * 128 + d];
    }
}

__global__ void softmax128_k(const float* __restrict__ in, float* __restrict__ out)
{
    const int row  = blockIdx.x;
    const int lane = threadIdx.x;
    float2 v = ((const float2*)(in + (long)row * 128))[lane];
    float m = fmaxf(v.x, v.y);
    #pragma unroll
    for (int s = 1; s < 64; s <<= 1) m = fmaxf(m, __shfl_xor(m, s, 64));
    float ex = expf(v.x - m), ey = expf(v.y - m);
    float sum = ex + ey;
    #pragma unroll
    for (int s = 1; s < 64; s <<= 1) sum += __shfl_xor(sum, s, 64);
    float inv = 1.0f / sum;
    ((float2*)(out + (long)row * 128))[lane] = make_float2(ex * inv, ey * inv);
}

__global__ void logsig_k(const float* __restrict__ in, float* __restrict__ out, long n)
{
    long i = (long)blockIdx.x * blockDim.x + threadIdx.x;
    if (i < n) {
        float x = in[i];
        float l = log1pf(expf(-fabsf(x)));
        out[i] = (fminf(x, 0.f) - l) * 0.0625f;
    }
}

__global__ void softmax_causal_k(bf16* __restrict__ P)
{
    const int row  = blockIdx.x;
    const int qi   = row & 1023;
    const int lane = threadIdx.x;
    bf16* p = P + (long)row * 1024;
    const float scale = 0.08838834764831845f;  // 1/sqrt(128)
    float vals[16];
    float m = -3.0e38f;
    #pragma unroll
    for (int t = 0; t < 16; ++t) {
        int j = lane + t * 64;
        float x = (j <= qi) ? (float)p[j] * scale : -3.0e38f;
        vals[t] = x;
        m = fmaxf(m, x);
    }
    #pragma unroll
    for (int s = 1; s < 64; s <<= 1) m = fmaxf(m, __shfl_xor(m, s, 64));
    float sum = 0.f;
    #pragma unroll
    for (int t = 0; t < 16; ++t) {
        float e = (vals[t] > -1.0e38f) ? expf(vals[t] - m) : 0.f;
        vals[t] = e;
        sum += e;
    }
    #pragma unroll
    for (int s = 1; s < 64; s <<= 1) sum += __shfl_xor(sum, s, 64);
    float inv = 1.f / sum;
    #pragma unroll
    for (int t = 0; t < 16; ++t) {
        int j = lane + t * 64;
        p[j] = (bf16)(vals[t] * inv);
    }
}

// ---------------------------------------------------------------------------
// Scan precompute kernels
// ---------------------------------------------------------------------------
// KT{hi,lo}[(achunk)][d][t] = split(KL[b, nc*64+t, kvh*128+d])
__global__ void ktrans_k(const float* __restrict__ KLb, bf16* __restrict__ KThi,
                         bf16* __restrict__ KTlo)
{
    long i = (long)blockIdx.x * blockDim.x + threadIdx.x;
    if (i < 1048576) {
        int t = (int)(i & 63);
        int d = (int)((i >> 6) & 127);
        int a = (int)(i >> 13);
        int b = a >> 6, kvh = (a >> 4) & 3, nc = a & 15;
        float x = KLb[((long)(b * 1024 + nc * 64 + t)) * 512 + kvh * 128 + d];
        bf16 h = (bf16)x;
        KThi[i] = h;
        KTlo[i] = (bf16)(x - (float)h);
    }
}

// A = tril_strict(K Kt) per kv-chunk (128). Ab{hi,lo} [a][t][s] (MFMA B-op);
// ATf [a][s][t] f32 (substitution rows). Masked entries explicit zeros.
__global__ void prepA_k(const float* __restrict__ KLb, bf16* __restrict__ Abhi,
                        bf16* __restrict__ Ablo, float* __restrict__ ATf)
{
    int a = blockIdx.x;
    int b = a >> 6, kvh = (a >> 4) & 3, nc = a & 15;
    const long rbase = ((long)(b * 1024 + nc * 64)) * 512 + kvh * 128;
    for (int e = threadIdx.x; e < 4096; e += 256) {
        int t = e >> 6, s = e & 63;
        float dot = 0.f;
        if (s < t) {
            const float* rt = KLb + rbase + (long)t * 512;
            const float* rs = KLb + rbase + (long)s * 512;
            for (int d = 0; d < 128; ++d) dot += rt[d] * rs[d];
        }
        bf16 hh = (bf16)dot;
        Abhi[(long)a * 4096 + t * 64 + s] = hh;
        Ablo[(long)a * 4096 + t * 64 + s] = (bf16)(dot - (float)hh);
        ATf[(long)a * 4096 + s * 64 + t] = dot;
    }
}

// Aq = tril_inclusive(Q Kt) per chunk (512), split hi/lo bf16, [c][t][s].
__global__ void prepAq_k(const float* __restrict__ QLb, const float* __restrict__ KLb,
                         bf16* __restrict__ Aqhi, bf16* __restrict__ Aqlo)
{
    int c = blockIdx.x;
    int b = c >> 8, h = (c >> 4) & 15, nc = c & 15, kvh = h >> 2;
    const long qb = ((long)(b * 1024 + nc * 64)) * 2048 + h * 128;
    const long kb = ((long)(b * 1024 + nc * 64)) * 512 + kvh * 128;
    for (int e = threadIdx.x; e < 4096; e += 256) {
        int t = e >> 6, s = e & 63;
        float dot = 0.f;
        if (s <= t) {
            const float* rq = QLb + qb + (long)t * 2048;
            const float* rk = KLb + kb + (long)s * 512;
            for (int d = 0; d < 128; ++d) dot += rq[d] * rk[d];
        }
        bf16 hh = (bf16)dot;
        Aqhi[(long)c * 4096 + t * 64 + s] = hh;
        Aqlo[(long)c * 4096 + t * 64 + s] = (bf16)(dot - (float)hh);
    }
}

// ---------------------------------------------------------------------------
// Sequential chunked delta-rule scan.
// grid = 8 blocks x 64 threads; block bi owns value-columns [16*bi, 16*bi+16).
// State S (128 x 16 fp32) lives permanently in MFMA accumulators.
// v/g loads use the GLOBAL column jglob (R2 bug was jloc). u kept as split
// bf16 hi/lo; S-update and corrections use 3-term split MFMAs.
// ---------------------------------------------------------------------------
__global__ __launch_bounds__(64, 1)
void seq_scan_k(const bf16* __restrict__ KLhi, const bf16* __restrict__ KLlo,
                const bf16* __restrict__ KThi, const bf16* __restrict__ KTlo,
                const bf16* __restrict__ Abhi, const bf16* __restrict__ Ablo,
                const float* __restrict__ ATf, const float* __restrict__ vf,
                const float* __restrict__ GLb,
                bf16* __restrict__ S0Thi, bf16* __restrict__ S0Tlo,
                bf16* __restrict__ uTghi, bf16* __restrict__ uTglo)
{
    __shared__ __align__(16) bf16  SThi[16 * 128];
    __shared__ __align__(16) bf16  STlo[16 * 128];
    __shared__ __align__(16) bf16  uThi[16 * 64];
    __shared__ __align__(16) bf16  uTlo[16 * 64];
    __shared__ __align__(16) float xb[64 * 16];

    const int lane  = threadIdx.x;
    const int jloc  = lane & 15;
    const int kq    = lane >> 4;          // quad 0..3
    const int jglob = blockIdx.x * 16 + jloc;

    // zero LDS state; zero S0T[0] slice for this block's columns
    for (int i = lane; i < 16 * 128; i += 64) { SThi[i] = (bf16)0.f; STlo[i] = (bf16)0.f; }
    for (int i = lane; i < 16 * 128; i += 64) {
        int j = i >> 7, d = i & 127;
        long off = (long)(blockIdx.x * 16 + j) * 128 + d;
        S0Thi[off] = (bf16)0.f;
        S0Tlo[off] = (bf16)0.f;
    }

    f32x4 S[8];
    #pragma unroll
    for (int m = 0; m < 8; ++m) S[m] = (f32x4){0.f, 0.f, 0.f, 0.f};

    for (int c = 0; c < NCHUNK; ++c) {
        const int b = c >> 8, h = (c >> 4) & 15, nc = c & 15;
        const int kvh = h >> 2, n0 = nc * 64;
        const long krow0  = ((long)(b * 1024 + n0)) * 512 + kvh * 128;   // KL rows, stride 512
        const int  achunk = (b * 4 + kvh) * 16 + nc;
        const long abase  = (long)achunk * 4096;
        const long ktbase = (long)achunk * 8192;                         // KT [d][t]

        // ---- W = K * S0 (3-MFMA split) ----
        f32x4 W[4];
        #pragma unroll
        for (int m = 0; m < 4; ++m) W[m] = (f32x4){0.f, 0.f, 0.f, 0.f};
        #pragma unroll
        for (int ki = 0; ki < 4; ++ki) {
            bf16x8 sh = *(const bf16x8*)&SThi[jloc * 128 + ki * 32 + kq * 8];
            bf16x8 sl = *(const bf16x8*)&STlo[jloc * 128 + ki * 32 + kq * 8];
            #pragma unroll
            for (int m = 0; m < 4; ++m) {
                long ko = krow0 + (long)(m * 16 + jloc) * 512 + ki * 32 + kq * 8;
                bf16x8 kh = *(const bf16x8*)(KLhi + ko);
                bf16x8 kl = *(const bf16x8*)(KLlo + ko);
                W[m] = __builtin_amdgcn_mfma_f32_16x16x32_bf16(kh, sh, W[m], 0, 0, 0);
                W[m] = __builtin_amdgcn_mfma_f32_16x16x32_bf16(kl, sh, W[m], 0, 0, 0);
                W[m] = __builtin_amdgcn_mfma_f32_16x16x32_bf16(kh, sl, W[m], 0, 0, 0);
            }
        }
        // epilogue: x[t][j] = W   (C/D: col=lane&15=j, row=kq*4+r)
        #pragma unroll
        for (int m = 0; m < 4; ++m)
            #pragma unroll
            for (int r = 0; r < 4; ++r)
                xb[(m * 16 + kq * 4 + r) * 16 + jloc] = W[m][r];

        // KT fragments for the S-update (held in regs through the SB loop)
        bf16x8 kth[16], ktl[16];
        #pragma unroll
        for (int m = 0; m < 8; ++m)
            #pragma unroll
            for (int ki = 0; ki < 2; ++ki) {
                long o = ktbase + (long)(m * 16 + jloc) * 64 + ki * 32 + kq * 8;
                kth[m * 2 + ki] = *(const bf16x8*)(KThi + o);
                ktl[m * 2 + ki] = *(const bf16x8*)(KTlo + o);
            }

        // zero u buffers (cols 0..15 rewritten in SB0 before any read)
        {
            uint4 z = {0u, 0u, 0u, 0u};
            ((uint4*)uThi)[lane] = z; ((uint4*)uThi)[lane + 64] = z;
            ((uint4*)uTlo)[lane] = z; ((uint4*)uTlo)[lane + 64] = z;
        }

        // ---- 4 sub-blocks of 16 ----
        #pragma unroll
        for (int i = 0; i < 4; ++i) {
            const int T0 = i * 16;
            if (i > 0) {
                // cross-SB correction: corr[j][t] = sum_{s<16i} u[j][s]*A[t][s]
                const int K32 = (i + 1) >> 1;   // 1,1,2
                f32x4 corr = (f32x4){0.f, 0.f, 0.f, 0.f};
                for (int ki = 0; ki < K32; ++ki) {
                    bf16x8 uh = *(const bf16x8*)&uThi[jloc * 64 + ki * 32 + kq * 8];
                    bf16x8 ul = *(const bf16x8*)&uTlo[jloc * 64 + ki * 32 + kq * 8];
                    long ao = abase + (long)(T0 + jloc) * 64 + ki * 32 + kq * 8;
                    bf16x8 ah = *(const bf16x8*)(Abhi + ao);
                    bf16x8 al = *(const bf16x8*)(Ablo + ao);
                    corr = __builtin_amdgcn_mfma_f32_16x16x32_bf16(uh, ah, corr, 0, 0, 0);
                    corr = __builtin_amdgcn_mfma_f32_16x16x32_bf16(ul, ah, corr, 0, 0, 0);
                    corr = __builtin_amdgcn_mfma_f32_16x16x32_bf16(uh, al, corr, 0, 0, 0);
                }
                // D[m=j][n=t]: col=lane&15 -> t=T0+jloc ; rows j = kq*4+r. RMW into x.
                #pragma unroll
                for (int r = 0; r < 4; ++r)
                    xb[(T0 + jloc) * 16 + kq * 4 + r] += corr[r];
            }

            // V/B for this sub-block — GLOBAL column jglob (the R2 fix)
            float Vv[16], Bv[16];
            const long vrow0 = ((long)(b * 1024 + n0 + T0)) * 512 + kvh * 128 + jglob;
            #pragma unroll
            for (int s = 0; s < 16; ++s) {
                Vv[s] = vf[vrow0 + (long)s * 512];
                Bv[s] = GLb[vrow0 + (long)s * 512];
            }

            // AT row prefetch ring (depth 4), rows pre-masked (zeros at t<=s)
            float rb[4][16];
            #pragma unroll
            for (int p = 0; p < 4; ++p) {
                const float* rp = ATf + abase + (long)(T0 + p) * 64 + T0;
                #pragma unroll
                for (int g = 0; g < 4; ++g) {
                    float4 v4 = *(const float4*)(rp + g * 4);
                    rb[p][g * 4 + 0] = v4.x; rb[p][g * 4 + 1] = v4.y;
                    rb[p][g * 4 + 2] = v4.z; rb[p][g * 4 + 3] = v4.w;
                }
            }

            float acc[16];
            #pragma unroll
            for (int t = 0; t < 16; ++t) acc[t] = 0.f;

            #pragma unroll
            for (int s = 0; s < 16; ++s) {
                float xv = xb[(T0 + s) * 16 + jloc];
                float u = Bv[s] * (Vv[s] - xv - acc[s]);
                bf16 uh = (bf16)u;
                bf16 ul = (bf16)(u - (float)uh);
                if (lane < 16) {
                    uThi[jloc * 64 + T0 + s] = uh;
                    uTlo[jloc * 64 + T0 + s] = ul;
                }
                // acc[t] += AT[s][t]*u for t>s (pruned statically)
                #pragma unroll
                for (int t = 0; t < 16; ++t)
                    if (t > s) acc[t] += rb[s & 3][t] * u;
                // refill ring slot with row s+4 (clamped; unused slots harmless)
                {
                    int rr = T0 + s + 4; if (rr > 63) rr = 63;
                    const float* rp = ATf + abase + (long)rr * 64 + T0;
                    #pragma unroll
                    for (int g = 0; g < 4; ++g) {
                        float4 v4 = *(const float4*)(rp + g * 4);
                        rb[s & 3][g * 4 + 0] = v4.x; rb[s & 3][g * 4 + 1] = v4.y;
                        rb[s & 3][g * 4 + 2] = v4.z; rb[s & 3][g * 4 + 3] = v4.w;
                    }
                }
            }
        }

        // ---- S += Kt * u (3-term split) ----
        #pragma unroll
        for (int ki = 0; ki < 2; ++ki) {
            bf16x8 uh = *(const bf16x8*)&uThi[jloc * 64 + ki * 32 + kq * 8];
            bf16x8 ul = *(const bf16x8*)&uTlo[jloc * 64 + ki * 32 + kq * 8];
            #pragma unroll
            for (int m = 0; m < 8; ++m) {
                S[m] = __builtin_amdgcn_mfma_f32_16x16x32_bf16(kth[m * 2 + ki], uh, S[m], 0, 0, 0);
                S[m] = __builtin_amdgcn_mfma_f32_16x16x32_bf16(kth[m * 2 + ki], ul, S[m], 0, 0, 0);
                S[m] = __builtin_amdgcn_mfma_f32_16x16x32_bf16(ktl[m * 2 + ki], uh, S[m], 0, 0, 0);
            }
        }

        // ---- bulk u -> global (coalesced; [c][jglob][s] contiguous per block)
        {
            const uint4* uh4 = (const uint4*)uThi;
            const uint4* ul4 = (const uint4*)uTlo;
            uint4* gh = (uint4*)(uTghi + ((long)c * 128 + blockIdx.x * 16) * 64);
            uint4* gl = (uint4*)(uTglo + ((long)c * 128 + blockIdx.x * 16) * 64);
            gh[lane] = uh4[lane]; gh[lane + 64] = uh4[lane + 64];
            gl[lane] = ul4[lane]; gl[lane + 64] = ul4[lane + 64];
        }

        // ---- S split epilogue: ST (LDS, next chunk) + S0T[c+1] (global, pass 2)
        #pragma unroll
        for (int m = 0; m < 8; ++m) {
            bf16x4 h4, l4;
            #pragma unroll
            for (int r = 0; r < 4; ++r) {
                float v = S[m][r];
                bf16 hh = (bf16)v;
                h4[r] = hh;
                l4[r] = (bf16)(v - (float)hh);
            }
            int d0 = m * 16 + kq * 4;
            *(bf16x4*)&SThi[jloc * 128 + d0] = h4;
            *(bf16x4*)&STlo[jloc * 128 + d0] = l4;
            long goff = (long)(c + 1) * 16384 + (long)jglob * 128 + d0;
            *(bf16x4*)(S0Thi + goff) = h4;
            *(bf16x4*)(S0Tlo + goff) = l4;
        }
    }
}

// ---------------------------------------------------------------------------
// Pass 2 (fully parallel): o[t][j] = Q*S0_c + tril_incl(Aq)*u  per chunk.
// ---------------------------------------------------------------------------
__global__ __launch_bounds__(256)
void pass2_o_k(const bf16* __restrict__ QLhi, const bf16* __restrict__ QLlo,
               const bf16* __restrict__ S0Thi, const bf16* __restrict__ S0Tlo,
               const bf16* __restrict__ Aqhi, const bf16* __restrict__ Aqlo,
               const bf16* __restrict__ uTghi, const bf16* __restrict__ uTglo,
               float* __restrict__ O)
{
    const int c    = blockIdx.x >> 3;
    const int tg   = blockIdx.x & 7;
    const int wave = threadIdx.x >> 6;
    const int lane = threadIdx.x & 63;
    const int tt   = tg * 4 + wave;
    const int mt   = tt >> 3, nt = tt & 7;
    const int b = c >> 8, h = (c >> 4) & 15, nc = c & 15, n0 = nc * 64;
    const int kq = lane >> 4, l15 = lane & 15;

    const long qrow   = ((long)(b * 1024 + n0 + mt * 16 + l15)) * 2048 + h * 128;
    const long sbase  = (long)c * 16384 + (long)(nt * 16 + l15) * 128;
    const long aqbase = (long)c * 4096 + (long)(mt * 16 + l15) * 64;
    const long ubase  = ((long)(c * 128 + nt * 16 + l15)) * 64;

    f32x4 acc = {0.f, 0.f, 0.f, 0.f};
    #pragma unroll
    for (int ki = 0; ki < 4; ++ki) {
        bf16x8 qh = *(const bf16x8*)(QLhi + qrow + ki * 32 + kq * 8);
        bf16x8 ql = *(const bf16x8*)(QLlo + qrow + ki * 32 + kq * 8);
        bf16x8 sh = *(const bf16x8*)(S0Thi + sbase + ki * 32 + kq * 8);
        bf16x8 sl = *(const bf16x8*)(S0Tlo + sbase + ki * 32 + kq * 8);
        acc = __builtin_amdgcn_mfma_f32_16x16x32_bf16(qh, sh, acc, 0, 0, 0);
        acc = __builtin_amdgcn_mfma_f32_16x16x32_bf16(ql, sh, acc, 0, 0, 0);
        acc = __builtin_amdgcn_mfma_f32_16x16x32_bf16(qh, sl, acc, 0, 0, 0);
    }
    #pragma unroll
    for (int ki = 0; ki < 2; ++ki) {
        bf16x8 ah = *(const bf16x8*)(Aqhi + aqbase + ki * 32 + kq * 8);
        bf16x8 al = *(const bf16x8*)(Aqlo + aqbase + ki * 32 + kq * 8);
        bf16x8 uh = *(const bf16x8*)(uTghi + ubase + ki * 32 + kq * 8);
        bf16x8 ul = *(const bf16x8*)(uTglo + ubase + ki * 32 + kq * 8);
        acc = __builtin_amdgcn_mfma_f32_16x16x32_bf16(ah, uh, acc, 0, 0, 0);
        acc = __builtin_amdgcn_mfma_f32_16x16x32_bf16(al, uh, acc, 0, 0, 0);
        acc = __builtin_amdgcn_mfma_f32_16x16x32_bf16(ah, ul, acc, 0, 0, 0);
    }
    #pragma unroll
    for (int r = 0; r < 4; ++r)
        O[((long)c * 64 + mt * 16 + kq * 4 + r) * 128 + nt * 16 + l15] = acc[r];
}

// oComb[(b,n),(h,d)] = 0.5*(oLin[(b,h,n),d] + oBase[(b,h,n),d])  -> bf16
__global__ void combine_k(const float* __restrict__ oLin, const bf16* __restrict__ oBase,
                          bf16* __restrict__ oComb, long n)
{
    long i = (long)blockIdx.x * blockDim.x + threadIdx.x;
    if (i < n) {
        int d  = (int)(i & 127);
        int hh = (int)((i >> 7) & 15);
        int nn = (int)((i >> 11) & 1023);
        int b  = (int)(i >> 21);
        long src = ((long)((b * 16 + hh) * 1024 + nn)) * 128 + d;
        oComb[i] = (bf16)(0.5f * (oLin[src] + (float)oBase[src]));
    }
}

// ---------------------------------------------------------------------------
extern "C" void kernel_launch(void* const* d_in, const int* in_sizes, int n_in,
                              void* d_out, int out_size, void* d_ws, size_t ws_size,
                              hipStream_t stream)
{
    const float* hs = (const float*)d_in[0];
    const float* Wq = (const float*)d_in[1];
    const float* Wk = (const float*)d_in[2];
    const float* Wv = (const float*)d_in[3];
    const float* Wo = (const float*)d_in[4];

    char* base = (char*)d_ws;
    size_t off = 0;
    auto alloc = [&](size_t bytes) -> char* {
        char* r = base + off;
        off += (bytes + 255) & ~(size_t)255;
        return r;
    };

    bf16* hsHi  = (bf16*)alloc((long)TOK * 2048 * 2);
    bf16* hsLo  = (bf16*)alloc((long)TOK * 2048 * 2);
    bf16* WqTHi = (bf16*)alloc(2048L * 2048 * 2);
    bf16* WqTLo = (bf16*)alloc(2048L * 2048 * 2);
    bf16* WkTHi = (bf16*)alloc(512L * 2048 * 2);
    bf16* WkTLo = (bf16*)alloc(512L * 2048 * 2);
    bf16* WvTHi = (bf16*)alloc(512L * 2048 * 2);
    bf16* WvTLo = (bf16*)alloc(512L * 2048 * 2);
    bf16* WoTHi = (bf16*)alloc(2048L * 2048 * 2);
    bf16* WoTLo = (bf16*)alloc(2048L * 2048 * 2);
    float* qf   = (float*)alloc((long)TOK * 2048 * 4);
    float* kf   = (float*)alloc((long)TOK * 512 * 4);
    float* vf   = (float*)alloc((long)TOK * 512 * 4);
    float* QLb  = (float*)alloc((long)TOK * 2048 * 4);
    float* KLb  = (float*)alloc((long)TOK * 512 * 4);
    float* GLb  = (float*)alloc((long)TOK * 512 * 4);
    bf16* qhB   = (bf16*)alloc((long)TOK * 2048 * 2);
    bf16* khB   = (bf16*)alloc((long)TOK * 512 * 2);
    bf16* vT    = (bf16*)alloc(1048576L * 2);
    bf16* P     = (bf16*)alloc(8L * 1024 * 1024 * 2);
    float* oLin = (float*)alloc(32768L * 128 * 4);
    bf16* oBase = (bf16*)alloc(32768L * 128 * 2);
    bf16* oComb = (bf16*)alloc((long)TOK * 2048 * 2);
    // scan machinery
    bf16* KLhi  = (bf16*)alloc((long)TOK * 512 * 2);
    bf16* KLlo  = (bf16*)alloc((long)TOK * 512 * 2);
    bf16* QLhi  = (bf16*)alloc((long)TOK * 2048 * 2);
    bf16* QLlo  = (bf16*)alloc((long)TOK * 2048 * 2);
    bf16* KThi  = (bf16*)alloc(1048576L * 2);
    bf16* KTlo  = (bf16*)alloc(1048576L * 2);
    bf16* Abhi  = (bf16*)alloc(128L * 4096 * 2);
    bf16* Ablo  = (bf16*)alloc(128L * 4096 * 2);
    float* ATf  = (float*)alloc(128L * 4096 * 4);
    bf16* Aqhi  = (bf16*)alloc(512L * 4096 * 2);
    bf16* Aqlo  = (bf16*)alloc(512L * 4096 * 2);
    bf16* S0Thi = (bf16*)alloc(513L * 16384 * 2);
    bf16* S0Tlo = (bf16*)alloc(513L * 16384 * 2);
    bf16* uTghi = (bf16*)alloc(512L * 128 * 64 * 2);
    bf16* uTglo = (bf16*)alloc(512L * 128 * 64 * 2);

    const int T256 = 256;
    // casts / transposes
    cast_split_k<<<(TOK * 2048 + 255) / 256, T256, 0, stream>>>(hs, hsHi, hsLo, (long)TOK * 2048);
    transpose_split_k<<<(2048L * 2048 + 255) / 256, T256, 0, stream>>>(Wq, WqTHi, WqTLo, 2048, 2048);
    transpose_split_k<<<(2048L * 512 + 255) / 256, T256, 0, stream>>>(Wk, WkTHi, WkTLo, 2048, 512);
    transpose_split_k<<<(2048L * 512 + 255) / 256, T256, 0, stream>>>(Wv, WvTHi, WvTLo, 2048, 512);
    transpose_split_k<<<(2048L * 2048 + 255) / 256, T256, 0, stream>>>(Wo, WoTHi, WoTLo, 2048, 2048);

    // projections (split-bf16 ~ fp32 accuracy)
    gemm_bt<true, false><<<dim3(4096, 1, 1), T256, 0, stream>>>(
        hsHi, hsLo, WqTHi, WqTLo, qf, nullptr,
        2048, 2048, 2048, 2048, 2048, 2048, 0, 0, 0, 0, 0, 0, 1, 0, 0);
    gemm_bt<true, false><<<dim3(1024, 1, 1), T256, 0, stream>>>(
        hsHi, hsLo, WkTHi, WkTLo, kf, nullptr,
        2048, 512, 2048, 2048, 2048, 512, 0, 0, 0, 0, 0, 0, 1, 0, 0);
    gemm_bt<true, false><<<dim3(1024, 1, 1), T256, 0, stream>>>(
        hsHi, hsLo, WvTHi, WvTLo, vf, nullptr,
        2048, 512, 2048, 2048, 2048, 512, 0, 0, 0, 0, 0, 0, 1, 0, 0);

    // scan-input prep
    softmax128_k<<<32768, 64, 0, stream>>>(qf, QLb);
    softmax128_k<<<8192, 64, 0, stream>>>(kf, KLb);
    logsig_k<<<(1048576 + 255) / 256, T256, 0, stream>>>(kf, GLb, 1048576);

    // attention-branch inputs
    cast_k<<<(TOK * 2048 + 255) / 256, T256, 0, stream>>>(qf, qhB, (long)TOK * 2048);
    cast_k<<<(TOK * 512 + 255) / 256, T256, 0, stream>>>(kf, khB, (long)TOK * 512);
    vtrans_k<<<(1048576 + 255) / 256, T256, 0, stream>>>(vf, vT);

    // scan precompute
    cast_split_k<<<(TOK * 512 + 255) / 256, T256, 0, stream>>>(KLb, KLhi, KLlo, (long)TOK * 512);
    cast_split_k<<<(TOK * 2048 + 255) / 256, T256, 0, stream>>>(QLb, QLhi, QLlo, (long)TOK * 2048);
    ktrans_k<<<(1048576 + 255) / 256, T256, 0, stream>>>(KLb, KThi, KTlo);
    prepA_k<<<128, T256, 0, stream>>>(KLb, Abhi, Ablo, ATf);
    prepAq_k<<<512, T256, 0, stream>>>(QLb, KLb, Aqhi, Aqlo);

    // attention branch, chunked over 8 (b,h) pairs to bound the P buffer
    for (int z0 = 0; z0 < 32; z0 += 8) {
        gemm_bt<false, true><<<dim3(1024, 1, 8), T256, 0, stream>>>(
            qhB, nullptr, khB, nullptr, nullptr, P,
            1024, 1024, 128, 2048, 512, 1024,
            2097152L, 128L, 0L, 524288L, 128L, 1048576L, 16, 2, z0);
        softmax_causal_k<<<8192, 64, 0, stream>>>(P);
        gemm_bt<false, true><<<dim3(128, 1, 8), T256, 0, stream>>>(
            P, nullptr, vT, nullptr, nullptr, oBase + (long)z0 * 131072,
            1024, 128, 1024, 1024, 1024, 128,
            0L, 0L, 1048576L, 524288L, 131072L, 131072L, 16, 2, z0);
    }

    // chunked delta-rule scan: sequential chain + parallel output pass
    seq_scan_k<<<8, 64, 0, stream>>>(KLhi, KLlo, KThi, KTlo, Abhi, Ablo, ATf, vf, GLb,
                                     S0Thi, S0Tlo, uTghi, uTglo);
    pass2_o_k<<<4096, T256, 0, stream>>>(QLhi, QLlo, S0Thi, S0Tlo, Aqhi, Aqlo,
                                         uTghi, uTglo, oLin);

    // combine branches and output projection
    combine_k<<<(TOK * 2048 + 255) / 256, T256, 0, stream>>>(oLin, oBase, oComb, (long)TOK * 2048);
    gemm_bt<false, false><<<dim3(4096, 1, 1), T256, 0, stream>>>(
        oComb, nullptr, WoTHi, nullptr, (float*)d_out, nullptr,
        2048, 2048, 2048, 2048, 2048, 2048, 0, 0, 0, 0, 0, 0, 1, 0, 0);
}